// Round 1
// baseline (2266.948 us; speedup 1.0000x reference)
//
#include <hip/hip_runtime.h>
#include <cmath>

#define D_MODEL 1536
#define N_HEADS 16
#define HEAD_DIM 96
#define SEQ 2048
#define BATCH 2
#define M_TOTAL (BATCH * SEQ)   // 4096
#define N_QKV (3 * D_MODEL)     // 4608

// ---------------------------------------------------------------------------
// GEMM C = A @ B^T, A [M][K] row-major, B [N][K] row-major (NT layout).
// 128x128 tile, BK=8, 256 threads, 8x8 microtile per thread.
// Two variants differing only in epilogue: qkv-scatter vs plain store.
// ---------------------------------------------------------------------------

__global__ __launch_bounds__(256) void gemm_qkv_kernel(
    const float* __restrict__ X,   // [4096][1536]
    const float* __restrict__ W,   // [4608][1536]
    float* __restrict__ qb, float* __restrict__ kb, float* __restrict__ vb)
{
    __shared__ __align__(16) float As[8][128];
    __shared__ __align__(16) float Bs[8][128];
    const int t  = threadIdx.x;
    const int m0 = blockIdx.y * 128;
    const int n0 = blockIdx.x * 128;
    const int tx = t & 15;
    const int ty = t >> 4;
    const int ar = t >> 1;
    const int ac = (t & 1) << 2;
    const float* Xp = X + (size_t)(m0 + ar) * D_MODEL + ac;
    const float* Wp = W + (size_t)(n0 + ar) * D_MODEL + ac;

    float acc[8][8];
#pragma unroll
    for (int i = 0; i < 8; ++i)
#pragma unroll
        for (int j = 0; j < 8; ++j) acc[i][j] = 0.f;

    for (int k0 = 0; k0 < D_MODEL; k0 += 8) {
        float4 av = *(const float4*)(Xp + k0);
        float4 bv = *(const float4*)(Wp + k0);
        __syncthreads();
        As[ac + 0][ar] = av.x; As[ac + 1][ar] = av.y;
        As[ac + 2][ar] = av.z; As[ac + 3][ar] = av.w;
        Bs[ac + 0][ar] = bv.x; Bs[ac + 1][ar] = bv.y;
        Bs[ac + 2][ar] = bv.z; Bs[ac + 3][ar] = bv.w;
        __syncthreads();
#pragma unroll
        for (int kk = 0; kk < 8; ++kk) {
            float4 a0 = *(const float4*)&As[kk][ty * 8];
            float4 a1 = *(const float4*)&As[kk][ty * 8 + 4];
            float4 b0 = *(const float4*)&Bs[kk][tx * 8];
            float4 b1 = *(const float4*)&Bs[kk][tx * 8 + 4];
            float a[8] = {a0.x, a0.y, a0.z, a0.w, a1.x, a1.y, a1.z, a1.w};
            float b[8] = {b0.x, b0.y, b0.z, b0.w, b1.x, b1.y, b1.z, b1.w};
#pragma unroll
            for (int i = 0; i < 8; ++i)
#pragma unroll
                for (int j = 0; j < 8; ++j)
                    acc[i][j] = fmaf(a[i], b[j], acc[i][j]);
        }
    }

    // epilogue: scatter into q/k/v, layout [b][h][s][96]
    // n decomposes as (which = n/1536, head = (n%1536)/96, d = n%96);
    // an aligned 8-wide span never crosses a 96-boundary (96 % 8 == 0).
    const int nb    = n0 + tx * 8;
    const int which = nb / D_MODEL;
    const int rem   = nb % D_MODEL;
    const int head  = rem / HEAD_DIM;
    const int d0    = rem % HEAD_DIM;
    float* dst = (which == 0) ? qb : (which == 1) ? kb : vb;
#pragma unroll
    for (int i = 0; i < 8; ++i) {
        const int rm = m0 + ty * 8 + i;
        const int bb = rm >> 11;           // / 2048
        const int ss = rm & (SEQ - 1);
        float* p = dst + (((size_t)(bb * N_HEADS + head) * SEQ + ss) * HEAD_DIM + d0);
        *(float4*)(p)     = make_float4(acc[i][0], acc[i][1], acc[i][2], acc[i][3]);
        *(float4*)(p + 4) = make_float4(acc[i][4], acc[i][5], acc[i][6], acc[i][7]);
    }
}

__global__ __launch_bounds__(256) void gemm_out_kernel(
    const float* __restrict__ A,   // [4096][1536] attn output
    const float* __restrict__ W,   // [1536][1536] w_out
    float* __restrict__ C)         // [4096][1536]
{
    __shared__ __align__(16) float As[8][128];
    __shared__ __align__(16) float Bs[8][128];
    const int t  = threadIdx.x;
    const int m0 = blockIdx.y * 128;
    const int n0 = blockIdx.x * 128;
    const int tx = t & 15;
    const int ty = t >> 4;
    const int ar = t >> 1;
    const int ac = (t & 1) << 2;
    const float* Ap = A + (size_t)(m0 + ar) * D_MODEL + ac;
    const float* Wp = W + (size_t)(n0 + ar) * D_MODEL + ac;

    float acc[8][8];
#pragma unroll
    for (int i = 0; i < 8; ++i)
#pragma unroll
        for (int j = 0; j < 8; ++j) acc[i][j] = 0.f;

    for (int k0 = 0; k0 < D_MODEL; k0 += 8) {
        float4 av = *(const float4*)(Ap + k0);
        float4 bv = *(const float4*)(Wp + k0);
        __syncthreads();
        As[ac + 0][ar] = av.x; As[ac + 1][ar] = av.y;
        As[ac + 2][ar] = av.z; As[ac + 3][ar] = av.w;
        Bs[ac + 0][ar] = bv.x; Bs[ac + 1][ar] = bv.y;
        Bs[ac + 2][ar] = bv.z; Bs[ac + 3][ar] = bv.w;
        __syncthreads();
#pragma unroll
        for (int kk = 0; kk < 8; ++kk) {
            float4 a0 = *(const float4*)&As[kk][ty * 8];
            float4 a1 = *(const float4*)&As[kk][ty * 8 + 4];
            float4 b0 = *(const float4*)&Bs[kk][tx * 8];
            float4 b1 = *(const float4*)&Bs[kk][tx * 8 + 4];
            float a[8] = {a0.x, a0.y, a0.z, a0.w, a1.x, a1.y, a1.z, a1.w};
            float b[8] = {b0.x, b0.y, b0.z, b0.w, b1.x, b1.y, b1.z, b1.w};
#pragma unroll
            for (int i = 0; i < 8; ++i)
#pragma unroll
                for (int j = 0; j < 8; ++j)
                    acc[i][j] = fmaf(a[i], b[j], acc[i][j]);
        }
    }
#pragma unroll
    for (int i = 0; i < 8; ++i) {
        const int rm = m0 + ty * 8 + i;
        float* p = C + (size_t)rm * D_MODEL + n0 + tx * 8;
        *(float4*)(p)     = make_float4(acc[i][0], acc[i][1], acc[i][2], acc[i][3]);
        *(float4*)(p + 4) = make_float4(acc[i][4], acc[i][5], acc[i][6], acc[i][7]);
    }
}

// ---------------------------------------------------------------------------
// Leech rotation: in-place, each thread owns one 24-float block.
// out[j] = sum_i in[i] * kern[i*24+j]   (einsum 'ni,ij->nj')
// ---------------------------------------------------------------------------
__global__ __launch_bounds__(256) void leech_rot_kernel(
    float* __restrict__ buf, const float* __restrict__ kern, int nblk)
{
    __shared__ float Kl[576];
    const int t = threadIdx.x;
    for (int i = t; i < 576; i += 256) Kl[i] = kern[i];
    __syncthreads();
    const int idx = blockIdx.x * 256 + t;
    if (idx >= nblk) return;
    float* p = buf + (size_t)idx * 24;
    float in[24];
#pragma unroll
    for (int i = 0; i < 24; ++i) in[i] = p[i];
#pragma unroll
    for (int j = 0; j < 24; ++j) {
        float s = 0.f;
#pragma unroll
        for (int i = 0; i < 24; ++i) s = fmaf(in[i], Kl[i * 24 + j], s);
        p[j] = s;
    }
}

// ---------------------------------------------------------------------------
// Flash attention, fp32. One block = (64 queries) x one (b,h).
// BK=32 keys per iteration, online softmax, O held in registers
// (24 floats/thread: thread t owns row t/4, dims (t%4)*24 .. +23).
// ---------------------------------------------------------------------------
#define BQ 64
#define BKT 32

__global__ __launch_bounds__(256) void flash_kernel(
    const float* __restrict__ Q, const float* __restrict__ K,
    const float* __restrict__ V, float* __restrict__ O)
{
    __shared__ float Qs[BQ][97];
    __shared__ float Ks[BKT][97];
    __shared__ __align__(16) float Vs[BKT][96];
    __shared__ float Ps[BQ][33];
    __shared__ float mrow[BQ], lrow[BQ], arow[BQ];

    const int t  = threadIdx.x;
    const int h  = blockIdx.y;
    const int bb = blockIdx.z;
    const int q0 = blockIdx.x * BQ;
    const size_t bh_off = ((size_t)bb * N_HEADS + h) * SEQ * HEAD_DIM;
    const float* Qb = Q + bh_off + (size_t)q0 * HEAD_DIM;
    const float* Kb = K + bh_off;
    const float* Vb = V + bh_off;
    const float scale = 0.10206207261596577f;  // 96^-0.5

    // load Q tile, pre-scaled
    {
        const int r = t >> 2;
        const int c = (t & 3) * 24;
        const float4* src = (const float4*)(Qb + r * HEAD_DIM + c);
#pragma unroll
        for (int j = 0; j < 6; ++j) {
            float4 vv = src[j];
            Qs[r][c + 4 * j + 0] = vv.x * scale;
            Qs[r][c + 4 * j + 1] = vv.y * scale;
            Qs[r][c + 4 * j + 2] = vv.z * scale;
            Qs[r][c + 4 * j + 3] = vv.w * scale;
        }
    }
    if (t < BQ) { mrow[t] = -INFINITY; lrow[t] = 0.f; }

    float o[24];
#pragma unroll
    for (int j = 0; j < 24; ++j) o[j] = 0.f;

    const int trow = t >> 3;        // S rows trow*2, trow*2+1
    const int tcol = (t & 7) * 4;   // S cols tcol..tcol+3
    const int orow = t >> 2;        // O row
    const int od0  = (t & 3) * 24;  // O dim base
    const int kvr  = t >> 3;        // K/V staging row
    const int kvc  = (t & 7) * 12;  // K/V staging col base

    for (int kt = 0; kt < SEQ / BKT; ++kt) {
        __syncthreads();  // previous iteration's readers of Ks/Vs/Ps done
        {
            const float* kp = Kb + (size_t)(kt * BKT + kvr) * HEAD_DIM + kvc;
            const float* vp = Vb + (size_t)(kt * BKT + kvr) * HEAD_DIM + kvc;
#pragma unroll
            for (int j = 0; j < 3; ++j) {
                float4 kv = *(const float4*)(kp + 4 * j);
                Ks[kvr][kvc + 4 * j + 0] = kv.x;
                Ks[kvr][kvc + 4 * j + 1] = kv.y;
                Ks[kvr][kvc + 4 * j + 2] = kv.z;
                Ks[kvr][kvc + 4 * j + 3] = kv.w;
                *(float4*)&Vs[kvr][kvc + 4 * j] = *(const float4*)(vp + 4 * j);
            }
        }
        __syncthreads();
        // S = (Q*scale) @ K^T, 2x4 microtile per thread
        {
            float sa[2][4];
#pragma unroll
            for (int i = 0; i < 2; ++i)
#pragma unroll
                for (int j = 0; j < 4; ++j) sa[i][j] = 0.f;
            const int r0 = trow * 2;
            for (int d = 0; d < HEAD_DIM; ++d) {
                float qa = Qs[r0][d];
                float qc = Qs[r0 + 1][d];
                float k0 = Ks[tcol + 0][d];
                float k1 = Ks[tcol + 1][d];
                float k2 = Ks[tcol + 2][d];
                float k3 = Ks[tcol + 3][d];
                sa[0][0] = fmaf(qa, k0, sa[0][0]);
                sa[0][1] = fmaf(qa, k1, sa[0][1]);
                sa[0][2] = fmaf(qa, k2, sa[0][2]);
                sa[0][3] = fmaf(qa, k3, sa[0][3]);
                sa[1][0] = fmaf(qc, k0, sa[1][0]);
                sa[1][1] = fmaf(qc, k1, sa[1][1]);
                sa[1][2] = fmaf(qc, k2, sa[1][2]);
                sa[1][3] = fmaf(qc, k3, sa[1][3]);
            }
#pragma unroll
            for (int i = 0; i < 2; ++i)
#pragma unroll
                for (int j = 0; j < 4; ++j)
                    Ps[r0 + i][tcol + j] = sa[i][j];
        }
        __syncthreads();
        // online softmax per row (one thread per row)
        if (t < BQ) {
            float mold = mrow[t];
            float mx = mold;
            for (int c2 = 0; c2 < BKT; ++c2) mx = fmaxf(mx, Ps[t][c2]);
            float alpha = __expf(mold - mx);
            float ls = 0.f;
            for (int c2 = 0; c2 < BKT; ++c2) {
                float pv = __expf(Ps[t][c2] - mx);
                Ps[t][c2] = pv;
                ls += pv;
            }
            mrow[t] = mx;
            lrow[t] = lrow[t] * alpha + ls;
            arow[t] = alpha;
        }
        __syncthreads();
        // O = O*alpha + P @ V
        {
            float alpha = arow[orow];
#pragma unroll
            for (int j = 0; j < 24; ++j) o[j] *= alpha;
            for (int c2 = 0; c2 < BKT; ++c2) {
                float pv = Ps[orow][c2];
                const float4* vp = (const float4*)&Vs[c2][od0];
#pragma unroll
                for (int jj = 0; jj < 6; ++jj) {
                    float4 vv = vp[jj];
                    o[jj * 4 + 0] = fmaf(pv, vv.x, o[jj * 4 + 0]);
                    o[jj * 4 + 1] = fmaf(pv, vv.y, o[jj * 4 + 1]);
                    o[jj * 4 + 2] = fmaf(pv, vv.z, o[jj * 4 + 2]);
                    o[jj * 4 + 3] = fmaf(pv, vv.w, o[jj * 4 + 3]);
                }
            }
        }
    }
    // write attn output, layout [b][s][h][d] == [4096][1536] rows
    {
        float linv = 1.0f / lrow[orow];
        float* dst = O + (((size_t)bb * SEQ + q0 + orow) * N_HEADS + h) * HEAD_DIM + od0;
#pragma unroll
        for (int jj = 0; jj < 6; ++jj) {
            *(float4*)(dst + jj * 4) = make_float4(o[jj * 4 + 0] * linv,
                                                   o[jj * 4 + 1] * linv,
                                                   o[jj * 4 + 2] * linv,
                                                   o[jj * 4 + 3] * linv);
        }
    }
}

// ---------------------------------------------------------------------------

extern "C" void kernel_launch(void* const* d_in, const int* in_sizes, int n_in,
                              void* d_out, int out_size, void* d_ws, size_t ws_size,
                              hipStream_t stream)
{
    const float* x      = (const float*)d_in[0];
    const float* w_qkv  = (const float*)d_in[1];
    const float* w_out  = (const float*)d_in[2];
    const float* leech  = (const float*)d_in[3];
    float* out = (float*)d_out;
    float* ws  = (float*)d_ws;

    const size_t S1 = (size_t)BATCH * N_HEADS * SEQ * HEAD_DIM;  // 6291456 floats
    float* qb   = ws;
    float* kb   = ws + S1;
    float* vb   = ws + 2 * S1;
    float* attn = ws + 3 * S1;   // [4096][1536], 6291456 floats

    // 1) qkv = x @ w_qkv^T, scattered into q/k/v [b][h][s][96]
    gemm_qkv_kernel<<<dim3(N_QKV / 128, M_TOTAL / 128), 256, 0, stream>>>(
        x, w_qkv, qb, kb, vb);

    // 2) leech rotation in-place on q and k (contiguous: 2*S1 floats)
    const int nblk = (int)(2 * S1 / 24);  // 524288
    leech_rot_kernel<<<(nblk + 255) / 256, 256, 0, stream>>>(qb, leech, nblk);

    // 3) flash attention -> attn [b][s][h][96]
    flash_kernel<<<dim3(SEQ / BQ, N_HEADS, BATCH), 256, 0, stream>>>(
        qb, kb, vb, attn);

    // 4) out = attn @ w_out^T
    gemm_out_kernel<<<dim3(D_MODEL / 128, M_TOTAL / 128), 256, 0, stream>>>(
        attn, w_out, out);
}

// Round 2
// 369.670 us; speedup vs baseline: 6.1324x; 6.1324x over previous
//
#include <hip/hip_runtime.h>
#include <cmath>

#define D_MODEL 1536
#define N_HEADS 16
#define HEAD_DIM 96
#define SEQ 2048
#define BATCH 2
#define M_TOTAL 4096
#define N_QKV 4608
#define QSCALE 0.10206207261596577f  // 96^-0.5

typedef unsigned short ushort_t;
typedef __attribute__((ext_vector_type(8))) short bf16x8;
typedef __attribute__((ext_vector_type(4))) float f32x4;

static __device__ __forceinline__ ushort_t f2bf(float f) {
    unsigned u = __builtin_bit_cast(unsigned, f);
    u += 0x7fffu + ((u >> 16) & 1u);   // RNE
    return (ushort_t)(u >> 16);
}

typedef const __attribute__((address_space(1))) unsigned int* gas_t;
typedef __attribute__((address_space(3))) unsigned int* las_t;
static __device__ __forceinline__ void gld_lds16(const void* g, void* l) {
    // async global->LDS, 16B/lane; LDS dest = wave-uniform base + lane*16
    __builtin_amdgcn_global_load_lds((gas_t)g, (las_t)l, 16, 0, 0);
}

#define MFMA16(a, b, c) __builtin_amdgcn_mfma_f32_16x16x32_bf16(a, b, c, 0, 0, 0)

// ---------------------------------------------------------------------------
// fp32 -> bf16 convert, 4 elems/thread
// ---------------------------------------------------------------------------
__global__ __launch_bounds__(256) void convert_f32_bf16(
    const float* __restrict__ in, ushort_t* __restrict__ out, int n)
{
    const int i = (blockIdx.x * 256 + threadIdx.x) * 4;
    if (i >= n) return;
    float4 v = *(const float4*)(in + i);
    ushort4 o;
    o.x = f2bf(v.x); o.y = f2bf(v.y); o.z = f2bf(v.z); o.w = f2bf(v.w);
    *(ushort4*)(out + i) = o;
}

// ---------------------------------------------------------------------------
// w_qkv prep: rows 0..3071 (q,k sections) get the leech rotation folded in:
// W'[R+j][k] = sum_i Kern[i][j] * W[R+i][k] for each aligned 24-row group R.
// v section (rows 3072..4607) is converted as-is. Output bf16.
// ---------------------------------------------------------------------------
__global__ __launch_bounds__(256) void prep_wqkv(
    const float* __restrict__ W, const float* __restrict__ Kern,
    ushort_t* __restrict__ Wb)
{
    __shared__ float Kl[576];
    const int t = threadIdx.x;
    for (int i = t; i < 576; i += 256) Kl[i] = Kern[i];
    __syncthreads();
    const int g = blockIdx.y;                  // 24-row group, 0..191
    const int k = blockIdx.x * 256 + t;        // column 0..1535
    const float* src = W + (size_t)g * 24 * D_MODEL + k;
    ushort_t* dst = Wb + (size_t)g * 24 * D_MODEL + k;
    if (g < 128) {
        float in[24];
#pragma unroll
        for (int i = 0; i < 24; ++i) in[i] = src[(size_t)i * D_MODEL];
#pragma unroll
        for (int j = 0; j < 24; ++j) {
            float s = 0.f;
#pragma unroll
            for (int i = 0; i < 24; ++i) s = fmaf(in[i], Kl[i * 24 + j], s);
            dst[(size_t)j * D_MODEL] = f2bf(s);
        }
    } else {
#pragma unroll
        for (int i = 0; i < 24; ++i) dst[(size_t)i * D_MODEL] = f2bf(src[(size_t)i * D_MODEL]);
    }
}

// ---------------------------------------------------------------------------
// bf16 MFMA GEMM, C = A @ B^T (both row-major [.,K=1536] bf16).
// 128x128 tile, BK=32, 256 thr = 4 waves (2x2), 4x4 16x16 tiles per wave.
// Staging via global_load_lds width=16.
// ---------------------------------------------------------------------------
__global__ __launch_bounds__(256, 3) void gemm_qkv_bf16(
    const ushort_t* __restrict__ X, const ushort_t* __restrict__ W,
    ushort_t* __restrict__ qb, ushort_t* __restrict__ kb, ushort_t* __restrict__ vb)
{
    __shared__ ushort_t As[128 * 32];
    __shared__ ushort_t Bs[128 * 32];
    const int t = threadIdx.x;
    const int lane = t & 63, w = t >> 6;
    const int c = lane & 15, qd = lane >> 4;
    const int m0 = blockIdx.y * 128, n0 = blockIdx.x * 128;
    const int wr = (w >> 1) * 64, wc = (w & 1) * 64;
    const int sr = lane >> 2, sc = (lane & 3) * 16;
    const char* Xb = (const char*)X;
    const char* Wp = (const char*)W;
    const size_t rowb = 2 * D_MODEL;

    f32x4 acc[4][4];
#pragma unroll
    for (int i = 0; i < 4; ++i)
#pragma unroll
        for (int j = 0; j < 4; ++j) acc[i][j] = {0.f, 0.f, 0.f, 0.f};

    for (int k0 = 0; k0 < D_MODEL; k0 += 32) {
        __syncthreads();
#pragma unroll
        for (int j = 0; j < 2; ++j) {
            const int g = w * 2 + j;
            gld_lds16(Xb + (size_t)(m0 + g * 16 + sr) * rowb + k0 * 2 + sc,
                      (char*)As + g * 1024);
            gld_lds16(Wp + (size_t)(n0 + g * 16 + sr) * rowb + k0 * 2 + sc,
                      (char*)Bs + g * 1024);
        }
        __syncthreads();
        bf16x8 af[4], bfr[4];
#pragma unroll
        for (int i = 0; i < 4; ++i)
            af[i] = *(const bf16x8*)&As[(wr + i * 16 + c) * 32 + qd * 8];
#pragma unroll
        for (int j = 0; j < 4; ++j)
            bfr[j] = *(const bf16x8*)&Bs[(wc + j * 16 + c) * 32 + qd * 8];
#pragma unroll
        for (int i = 0; i < 4; ++i)
#pragma unroll
            for (int j = 0; j < 4; ++j)
                acc[i][j] = MFMA16(af[i], bfr[j], acc[i][j]);
    }
    // epilogue: scatter bf16 into q/k/v [b][h][s][96]; q gets QSCALE folded in
#pragma unroll
    for (int j = 0; j < 4; ++j) {
        const int n = n0 + wc + j * 16 + c;
        const int which = n / D_MODEL;
        const int rem = n % D_MODEL;
        const int head = rem / HEAD_DIM;
        const int d = rem % HEAD_DIM;
        ushort_t* dst = which == 0 ? qb : which == 1 ? kb : vb;
        const float sc2 = which == 0 ? QSCALE : 1.0f;
#pragma unroll
        for (int i = 0; i < 4; ++i)
#pragma unroll
            for (int r = 0; r < 4; ++r) {
                const int m = m0 + wr + i * 16 + qd * 4 + r;
                const int b_ = m >> 11, s_ = m & (SEQ - 1);
                dst[((size_t)(b_ * N_HEADS + head) * SEQ + s_) * HEAD_DIM + d] =
                    f2bf(acc[i][j][r] * sc2);
            }
    }
}

__global__ __launch_bounds__(256, 3) void gemm_out_bf16(
    const ushort_t* __restrict__ A, const ushort_t* __restrict__ W,
    float* __restrict__ C)
{
    __shared__ ushort_t As[128 * 32];
    __shared__ ushort_t Bs[128 * 32];
    const int t = threadIdx.x;
    const int lane = t & 63, w = t >> 6;
    const int c = lane & 15, qd = lane >> 4;
    const int m0 = blockIdx.y * 128, n0 = blockIdx.x * 128;
    const int wr = (w >> 1) * 64, wc = (w & 1) * 64;
    const int sr = lane >> 2, sc = (lane & 3) * 16;
    const char* Ab = (const char*)A;
    const char* Wp = (const char*)W;
    const size_t rowb = 2 * D_MODEL;

    f32x4 acc[4][4];
#pragma unroll
    for (int i = 0; i < 4; ++i)
#pragma unroll
        for (int j = 0; j < 4; ++j) acc[i][j] = {0.f, 0.f, 0.f, 0.f};

    for (int k0 = 0; k0 < D_MODEL; k0 += 32) {
        __syncthreads();
#pragma unroll
        for (int j = 0; j < 2; ++j) {
            const int g = w * 2 + j;
            gld_lds16(Ab + (size_t)(m0 + g * 16 + sr) * rowb + k0 * 2 + sc,
                      (char*)As + g * 1024);
            gld_lds16(Wp + (size_t)(n0 + g * 16 + sr) * rowb + k0 * 2 + sc,
                      (char*)Bs + g * 1024);
        }
        __syncthreads();
        bf16x8 af[4], bfr[4];
#pragma unroll
        for (int i = 0; i < 4; ++i)
            af[i] = *(const bf16x8*)&As[(wr + i * 16 + c) * 32 + qd * 8];
#pragma unroll
        for (int j = 0; j < 4; ++j)
            bfr[j] = *(const bf16x8*)&Bs[(wc + j * 16 + c) * 32 + qd * 8];
#pragma unroll
        for (int i = 0; i < 4; ++i)
#pragma unroll
            for (int j = 0; j < 4; ++j)
                acc[i][j] = MFMA16(af[i], bfr[j], acc[i][j]);
    }
#pragma unroll
    for (int i = 0; i < 4; ++i)
#pragma unroll
        for (int j = 0; j < 4; ++j)
#pragma unroll
            for (int r = 0; r < 4; ++r)
                C[(size_t)(m0 + wr + i * 16 + qd * 4 + r) * D_MODEL + n0 + wc + j * 16 + c] =
                    acc[i][j][r];
}

// ---------------------------------------------------------------------------
// MFMA flash attention. Block = 128 queries x one (b,h); 4 waves x 32 queries.
// BK=64 keys/iter. Q frags in regs; K staged [64][96] via global_load_lds;
// V staged transposed Vt[96][72] (pad 8); P round-trips LDS per wave [32][72].
// q pre-scaled by 96^-0.5 at QKV epilogue.
// ---------------------------------------------------------------------------
__global__ __launch_bounds__(256, 2) void flash_bf16(
    const ushort_t* __restrict__ Q, const ushort_t* __restrict__ K,
    const ushort_t* __restrict__ V, ushort_t* __restrict__ attn)
{
    __shared__ ushort_t Ks[64 * 96];      // [key][d]
    __shared__ ushort_t Vt[96 * 72];      // [d][key], pad 64->72
    __shared__ ushort_t Ps[4][32 * 72];   // per wave [q][key], pad 64->72

    const int t = threadIdx.x;
    const int lane = t & 63, w = t >> 6;
    const int c = lane & 15, qd = lane >> 4;
    const int h = blockIdx.y, bb = blockIdx.z;
    const int q0 = blockIdx.x * 128;
    const size_t base = ((size_t)(bb * N_HEADS + h)) * SEQ * HEAD_DIM;
    const ushort_t* Qb = Q + base;
    const ushort_t* Kb = K + base;
    const ushort_t* Vb = V + base;

    // Q fragments in registers: rows q0 + w*32 + i*16 + c, k chunk kc
    bf16x8 aq[2][3];
#pragma unroll
    for (int i = 0; i < 2; ++i)
#pragma unroll
        for (int kc = 0; kc < 3; ++kc)
            aq[i][kc] = *(const bf16x8*)(Qb + (size_t)(q0 + w * 32 + i * 16 + c) * HEAD_DIM +
                                         kc * 32 + qd * 8);

    f32x4 oacc[2][6];
#pragma unroll
    for (int i = 0; i < 2; ++i)
#pragma unroll
        for (int jd = 0; jd < 6; ++jd) oacc[i][jd] = {0.f, 0.f, 0.f, 0.f};
    float mrow[2][4], lrow[2][4];
#pragma unroll
    for (int i = 0; i < 2; ++i)
#pragma unroll
        for (int r = 0; r < 4; ++r) { mrow[i][r] = -INFINITY; lrow[i][r] = 0.f; }

    // K staging addressing (12 wave-insts of 1024B over 64*192B tile)
    int kr[3], kcb[3];
#pragma unroll
    for (int jj = 0; jj < 3; ++jj) {
        const int o = (w * 3 + jj) * 1024 + lane * 16;
        kr[jj] = o / 192;
        kcb[jj] = o % 192;
    }
    const int vn = t & 63, vd = (t >> 6) * 24;  // Vt staging assignment

    for (int kt = 0; kt < SEQ / 64; ++kt) {
        __syncthreads();  // prior iter's K/Vt readers done
        const char* KbB = (const char*)(Kb + (size_t)kt * 64 * HEAD_DIM);
#pragma unroll
        for (int jj = 0; jj < 3; ++jj)
            gld_lds16(KbB + (size_t)kr[jj] * 192 + kcb[jj], (char*)Ks + (w * 3 + jj) * 1024);
        {
            const ushort_t* vsrc = Vb + (size_t)(kt * 64 + vn) * HEAD_DIM + vd;
#pragma unroll
            for (int jv = 0; jv < 3; ++jv) {
                bf16x8 vv = *(const bf16x8*)(vsrc + jv * 8);
#pragma unroll
                for (int e = 0; e < 8; ++e)
                    Vt[(vd + jv * 8 + e) * 72 + vn] = (ushort_t)vv[e];
            }
        }
        __syncthreads();

        // S = Q K^T : 2 row-tiles x 4 col-tiles x 3 k-chunks
        f32x4 sacc[2][4];
#pragma unroll
        for (int i = 0; i < 2; ++i)
#pragma unroll
            for (int j = 0; j < 4; ++j) sacc[i][j] = {0.f, 0.f, 0.f, 0.f};
#pragma unroll
        for (int kc = 0; kc < 3; ++kc) {
            bf16x8 bk[4];
#pragma unroll
            for (int j = 0; j < 4; ++j)
                bk[j] = *(const bf16x8*)&Ks[(j * 16 + c) * 96 + kc * 32 + qd * 8];
#pragma unroll
            for (int i = 0; i < 2; ++i)
#pragma unroll
                for (int j = 0; j < 4; ++j)
                    sacc[i][j] = MFMA16(aq[i][kc], bk[j], sacc[i][j]);
        }

        // online softmax (rows = i*16 + qd*4 + r; reduce across 16 lanes of quad)
        float al[2][4];
#pragma unroll
        for (int i = 0; i < 2; ++i)
#pragma unroll
            for (int r = 0; r < 4; ++r) {
                float mx = fmaxf(fmaxf(sacc[i][0][r], sacc[i][1][r]),
                                 fmaxf(sacc[i][2][r], sacc[i][3][r]));
#pragma unroll
                for (int mk = 1; mk <= 8; mk <<= 1)
                    mx = fmaxf(mx, __shfl_xor(mx, mk, 64));
                const float mold = mrow[i][r];
                const float mnew = fmaxf(mold, mx);
                const float a = __expf(mold - mnew);
                float ls = 0.f;
#pragma unroll
                for (int j = 0; j < 4; ++j) {
                    const float p = __expf(sacc[i][j][r] - mnew);
                    Ps[w][(i * 16 + qd * 4 + r) * 72 + j * 16 + c] = f2bf(p);
                    ls += p;
                }
#pragma unroll
                for (int mk = 1; mk <= 8; mk <<= 1)
                    ls += __shfl_xor(ls, mk, 64);
                mrow[i][r] = mnew;
                lrow[i][r] = lrow[i][r] * a + ls;
                al[i][r] = a;
            }

        // O = O*alpha + P V
#pragma unroll
        for (int i = 0; i < 2; ++i)
#pragma unroll
            for (int jd = 0; jd < 6; ++jd)
#pragma unroll
                for (int r = 0; r < 4; ++r) oacc[i][jd][r] *= al[i][r];
#pragma unroll
        for (int kc = 0; kc < 2; ++kc) {
            bf16x8 ap[2], bv[6];
#pragma unroll
            for (int i = 0; i < 2; ++i)
                ap[i] = *(const bf16x8*)&Ps[w][(i * 16 + c) * 72 + kc * 32 + qd * 8];
#pragma unroll
            for (int jd = 0; jd < 6; ++jd)
                bv[jd] = *(const bf16x8*)&Vt[(jd * 16 + c) * 72 + kc * 32 + qd * 8];
#pragma unroll
            for (int i = 0; i < 2; ++i)
#pragma unroll
                for (int jd = 0; jd < 6; ++jd)
                    oacc[i][jd] = MFMA16(ap[i], bv[jd], oacc[i][jd]);
        }
    }

    // epilogue: attn[b][s][h*96+d] bf16
#pragma unroll
    for (int i = 0; i < 2; ++i)
#pragma unroll
        for (int r = 0; r < 4; ++r) {
            const float linv = 1.0f / lrow[i][r];
            const int row = q0 + w * 32 + i * 16 + qd * 4 + r;
            ushort_t* dst = attn + ((size_t)(bb * SEQ + row)) * D_MODEL + h * HEAD_DIM;
#pragma unroll
            for (int jd = 0; jd < 6; ++jd)
                dst[jd * 16 + c] = f2bf(oacc[i][jd][r] * linv);
        }
}

// ---------------------------------------------------------------------------

extern "C" void kernel_launch(void* const* d_in, const int* in_sizes, int n_in,
                              void* d_out, int out_size, void* d_ws, size_t ws_size,
                              hipStream_t stream)
{
    const float* x     = (const float*)d_in[0];
    const float* w_qkv = (const float*)d_in[1];
    const float* w_out = (const float*)d_in[2];
    const float* leech = (const float*)d_in[3];
    float* out = (float*)d_out;
    char* ws = (char*)d_ws;

    ushort_t* xb    = (ushort_t*)(ws);                 // 4096*1536*2  = 12582912
    ushort_t* wqkvb = (ushort_t*)(ws + 12582912);      // 4608*1536*2  = 14155776
    ushort_t* woutb = (ushort_t*)(ws + 26738688);      // 1536*1536*2  =  4718592
    ushort_t* qb    = (ushort_t*)(ws + 31457280);      // 12582912 each
    ushort_t* kb    = (ushort_t*)(ws + 44040192);
    ushort_t* vb    = (ushort_t*)(ws + 56623104);
    ushort_t* attnb = (ushort_t*)(ws + 69206016);      // ends 81788928

    convert_f32_bf16<<<6144, 256, 0, stream>>>(x, xb, M_TOTAL * D_MODEL);
    prep_wqkv<<<dim3(6, 192), 256, 0, stream>>>(w_qkv, leech, wqkvb);
    convert_f32_bf16<<<2304, 256, 0, stream>>>(w_out, woutb, D_MODEL * D_MODEL);

    gemm_qkv_bf16<<<dim3(N_QKV / 128, M_TOTAL / 128), 256, 0, stream>>>(
        xb, wqkvb, qb, kb, vb);

    flash_bf16<<<dim3(SEQ / 128, N_HEADS, BATCH), 256, 0, stream>>>(
        qb, kb, vb, attnb);

    gemm_out_bf16<<<dim3(D_MODEL / 128, M_TOTAL / 128), 256, 0, stream>>>(
        attnb, woutb, out);
}

// Round 3
// 302.857 us; speedup vs baseline: 7.4852x; 1.2206x over previous
//
#include <hip/hip_runtime.h>
#include <cmath>

#define D_MODEL 1536
#define N_HEADS 16
#define HEAD_DIM 96
#define SEQ 2048
#define BATCH 2
#define M_TOTAL 4096
#define N_QKV 4608
// 96^-0.5 * log2(e): fold into q so softmax exp becomes a bare v_exp_f32 (2^x)
#define QK_LOG2E 0.14724449f

typedef unsigned short ushort_t;
typedef __attribute__((ext_vector_type(8))) short bf16x8;
typedef __attribute__((ext_vector_type(4))) float f32x4;

static __device__ __forceinline__ ushort_t f2bf(float f) {
    unsigned u = __builtin_bit_cast(unsigned, f);
    u += 0x7fffu + ((u >> 16) & 1u);   // RNE
    return (ushort_t)(u >> 16);
}

static __device__ __forceinline__ unsigned pk2bf(float lo, float hi) {
#if __has_builtin(__builtin_amdgcn_cvt_pk_bf16_f32)
    auto v = __builtin_amdgcn_cvt_pk_bf16_f32(lo, hi);
    return __builtin_bit_cast(unsigned, v);
#else
    return (unsigned)f2bf(lo) | ((unsigned)f2bf(hi) << 16);
#endif
}

static __device__ __forceinline__ float fast_exp2(float x) {
#if __has_builtin(__builtin_amdgcn_exp2f)
    return __builtin_amdgcn_exp2f(x);
#else
    return __expf(x * 0.69314718056f);
#endif
}

typedef const __attribute__((address_space(1))) unsigned int* gas_t;
typedef __attribute__((address_space(3))) unsigned int* las_t;
static __device__ __forceinline__ void gld_lds16(const void* g, void* l) {
    // async global->LDS, 16B/lane; global addr is PER-LANE, LDS dest = base + lane*16
    __builtin_amdgcn_global_load_lds((gas_t)g, (las_t)l, 16, 0, 0);
}

#define MFMA16(a, b, c) __builtin_amdgcn_mfma_f32_16x16x32_bf16(a, b, c, 0, 0, 0)

// ---------------------------------------------------------------------------
// fp32 -> bf16 convert, 4 elems/thread
// ---------------------------------------------------------------------------
__global__ __launch_bounds__(256) void convert_f32_bf16(
    const float* __restrict__ in, ushort_t* __restrict__ out, int n)
{
    const int i = (blockIdx.x * 256 + threadIdx.x) * 4;
    if (i >= n) return;
    float4 v = *(const float4*)(in + i);
    ushort4 o;
    o.x = f2bf(v.x); o.y = f2bf(v.y); o.z = f2bf(v.z); o.w = f2bf(v.w);
    *(ushort4*)(out + i) = o;
}

// ---------------------------------------------------------------------------
// w_qkv prep: q,k rows get the leech rotation folded in (output-feature-space
// rotation within aligned 24-row groups). v rows converted as-is.
// ---------------------------------------------------------------------------
__global__ __launch_bounds__(256) void prep_wqkv(
    const float* __restrict__ W, const float* __restrict__ Kern,
    ushort_t* __restrict__ Wb)
{
    __shared__ float Kl[576];
    const int t = threadIdx.x;
    for (int i = t; i < 576; i += 256) Kl[i] = Kern[i];
    __syncthreads();
    const int g = blockIdx.y;                  // 24-row group, 0..191
    const int k = blockIdx.x * 256 + t;        // column 0..1535
    const float* src = W + (size_t)g * 24 * D_MODEL + k;
    ushort_t* dst = Wb + (size_t)g * 24 * D_MODEL + k;
    if (g < 128) {
        float in[24];
#pragma unroll
        for (int i = 0; i < 24; ++i) in[i] = src[(size_t)i * D_MODEL];
#pragma unroll
        for (int j = 0; j < 24; ++j) {
            float s = 0.f;
#pragma unroll
            for (int i = 0; i < 24; ++i) s = fmaf(in[i], Kl[i * 24 + j], s);
            dst[(size_t)j * D_MODEL] = f2bf(s);
        }
    } else {
#pragma unroll
        for (int i = 0; i < 24; ++i) dst[(size_t)i * D_MODEL] = f2bf(src[(size_t)i * D_MODEL]);
    }
}

// ---------------------------------------------------------------------------
// bf16 MFMA GEMM, C = A @ B^T. 128x128 tile, BK=32, 4 waves, 4x4 16x16/wave.
// ---------------------------------------------------------------------------
__global__ __launch_bounds__(256, 3) void gemm_qkv_bf16(
    const ushort_t* __restrict__ X, const ushort_t* __restrict__ W,
    ushort_t* __restrict__ qb, ushort_t* __restrict__ kb, ushort_t* __restrict__ vb)
{
    __shared__ ushort_t As[128 * 32];
    __shared__ ushort_t Bs[128 * 32];
    const int t = threadIdx.x;
    const int lane = t & 63, w = t >> 6;
    const int c = lane & 15, qd = lane >> 4;
    const int m0 = blockIdx.y * 128, n0 = blockIdx.x * 128;
    const int wr = (w >> 1) * 64, wc = (w & 1) * 64;
    const int sr = lane >> 2, sc = (lane & 3) * 16;
    const char* Xb = (const char*)X;
    const char* Wp = (const char*)W;
    const size_t rowb = 2 * D_MODEL;

    f32x4 acc[4][4];
#pragma unroll
    for (int i = 0; i < 4; ++i)
#pragma unroll
        for (int j = 0; j < 4; ++j) acc[i][j] = {0.f, 0.f, 0.f, 0.f};

    for (int k0 = 0; k0 < D_MODEL; k0 += 32) {
        __syncthreads();
#pragma unroll
        for (int j = 0; j < 2; ++j) {
            const int g = w * 2 + j;
            gld_lds16(Xb + (size_t)(m0 + g * 16 + sr) * rowb + k0 * 2 + sc,
                      (char*)As + g * 1024);
            gld_lds16(Wp + (size_t)(n0 + g * 16 + sr) * rowb + k0 * 2 + sc,
                      (char*)Bs + g * 1024);
        }
        __syncthreads();
        bf16x8 af[4], bfr[4];
#pragma unroll
        for (int i = 0; i < 4; ++i)
            af[i] = *(const bf16x8*)&As[(wr + i * 16 + c) * 32 + qd * 8];
#pragma unroll
        for (int j = 0; j < 4; ++j)
            bfr[j] = *(const bf16x8*)&Bs[(wc + j * 16 + c) * 32 + qd * 8];
#pragma unroll
        for (int i = 0; i < 4; ++i)
#pragma unroll
            for (int j = 0; j < 4; ++j)
                acc[i][j] = MFMA16(af[i], bfr[j], acc[i][j]);
    }
    // epilogue: scatter bf16 into q/k/v [b][h][s][96]; q gets QK_LOG2E folded in
#pragma unroll
    for (int j = 0; j < 4; ++j) {
        const int n = n0 + wc + j * 16 + c;
        const int which = n / D_MODEL;
        const int rem = n % D_MODEL;
        const int head = rem / HEAD_DIM;
        const int d = rem % HEAD_DIM;
        ushort_t* dst = which == 0 ? qb : which == 1 ? kb : vb;
        const float sc2 = which == 0 ? QK_LOG2E : 1.0f;
#pragma unroll
        for (int i = 0; i < 4; ++i)
#pragma unroll
            for (int r = 0; r < 4; ++r) {
                const int m = m0 + wr + i * 16 + qd * 4 + r;
                const int b_ = m >> 11, s_ = m & (SEQ - 1);
                dst[((size_t)(b_ * N_HEADS + head) * SEQ + s_) * HEAD_DIM + d] =
                    f2bf(acc[i][j][r] * sc2);
            }
    }
}

__global__ __launch_bounds__(256, 3) void gemm_out_bf16(
    const ushort_t* __restrict__ A, const ushort_t* __restrict__ W,
    float* __restrict__ C)
{
    __shared__ ushort_t As[128 * 32];
    __shared__ ushort_t Bs[128 * 32];
    const int t = threadIdx.x;
    const int lane = t & 63, w = t >> 6;
    const int c = lane & 15, qd = lane >> 4;
    const int m0 = blockIdx.y * 128, n0 = blockIdx.x * 128;
    const int wr = (w >> 1) * 64, wc = (w & 1) * 64;
    const int sr = lane >> 2, sc = (lane & 3) * 16;
    const char* Ab = (const char*)A;
    const char* Wp = (const char*)W;
    const size_t rowb = 2 * D_MODEL;

    f32x4 acc[4][4];
#pragma unroll
    for (int i = 0; i < 4; ++i)
#pragma unroll
        for (int j = 0; j < 4; ++j) acc[i][j] = {0.f, 0.f, 0.f, 0.f};

    for (int k0 = 0; k0 < D_MODEL; k0 += 32) {
        __syncthreads();
#pragma unroll
        for (int j = 0; j < 2; ++j) {
            const int g = w * 2 + j;
            gld_lds16(Ab + (size_t)(m0 + g * 16 + sr) * rowb + k0 * 2 + sc,
                      (char*)As + g * 1024);
            gld_lds16(Wp + (size_t)(n0 + g * 16 + sr) * rowb + k0 * 2 + sc,
                      (char*)Bs + g * 1024);
        }
        __syncthreads();
        bf16x8 af[4], bfr[4];
#pragma unroll
        for (int i = 0; i < 4; ++i)
            af[i] = *(const bf16x8*)&As[(wr + i * 16 + c) * 32 + qd * 8];
#pragma unroll
        for (int j = 0; j < 4; ++j)
            bfr[j] = *(const bf16x8*)&Bs[(wc + j * 16 + c) * 32 + qd * 8];
#pragma unroll
        for (int i = 0; i < 4; ++i)
#pragma unroll
            for (int j = 0; j < 4; ++j)
                acc[i][j] = MFMA16(af[i], bfr[j], acc[i][j]);
    }
#pragma unroll
    for (int i = 0; i < 4; ++i)
#pragma unroll
        for (int j = 0; j < 4; ++j)
#pragma unroll
            for (int r = 0; r < 4; ++r)
                C[(size_t)(m0 + wr + i * 16 + qd * 4 + r) * D_MODEL + n0 + wc + j * 16 + c] =
                    acc[i][j][r];
}

// ---------------------------------------------------------------------------
// MFMA flash attention v3 (no-max softmax; S^T formulation).
// Block = 128 q x one (b,h); 4 waves x 32 q. BK=64 keys/iter.
//   S^T = K·Q^T  (A=K rows from chunk-major LDS, B=Q regs)
//   p = 2^s (scale·log2e folded into q); l via in-reg sum + 2 shuffles
//   P packed to LDS [q][k] as b64 writes (per-wave buffer, no barrier)
//   O^T = V^T·P^T (A=Vt rows, B=Ps rows)
// K staged chunk-major [12][64][8] via per-lane-gather global_load_lds
// (conflict-free reads); V prefetched through regs, transposed to Vt[96][72].
// ---------------------------------------------------------------------------
__global__ __launch_bounds__(256, 3) void flash_bf16(
    const ushort_t* __restrict__ Q, const ushort_t* __restrict__ K,
    const ushort_t* __restrict__ V, ushort_t* __restrict__ attn)
{
    __shared__ ushort_t Ks[12 * 64 * 8];  // chunk-major: (d-chunk, key, 8)
    __shared__ ushort_t Vt[96 * 72];      // [d][key], pad 64->72
    __shared__ ushort_t Ps[4][32 * 72];   // per-wave [q][k], pad 64->72

    const int t = threadIdx.x;
    const int lane = t & 63, w = t >> 6;
    const int c = lane & 15, qd = lane >> 4;
    const int h = blockIdx.y, bb = blockIdx.z;
    const int q0 = blockIdx.x * 128;
    const size_t base = ((size_t)(bb * N_HEADS + h)) * SEQ * HEAD_DIM;
    const ushort_t* Qb = Q + base;
    const char* Kb = (const char*)(K + base);
    const ushort_t* Vb = V + base;

    // Q B-operand fragments (resident all kernel): B[n=q][k=d]
    bf16x8 aq[2][3];
#pragma unroll
    for (int qi = 0; qi < 2; ++qi)
#pragma unroll
        for (int kc = 0; kc < 3; ++kc)
            aq[qi][kc] = *(const bf16x8*)(Qb +
                (size_t)(q0 + w * 32 + qi * 16 + c) * HEAD_DIM + kc * 32 + qd * 8);

    f32x4 oacc[6][2];
#pragma unroll
    for (int jd = 0; jd < 6; ++jd)
#pragma unroll
        for (int qi = 0; qi < 2; ++qi) oacc[jd][qi] = {0.f, 0.f, 0.f, 0.f};
    float lrow[2] = {0.f, 0.f};

    // V prefetch for kt=0: thread covers (key=lane, d = w*24..w*24+23)
    bf16x8 vreg[3];
    {
        const ushort_t* vp = Vb + (size_t)lane * HEAD_DIM + w * 24;
#pragma unroll
        for (int jv = 0; jv < 3; ++jv) vreg[jv] = *(const bf16x8*)(vp + jv * 8);
    }

    for (int kt = 0; kt < SEQ / 64; ++kt) {
        __syncthreads();  // prior iter's Ks/Vt readers done
        // issue async K[kt] staging, chunk-major, per-lane gather (stride 192B)
        {
            const char* kp = Kb + (size_t)kt * 64 * 192;
#pragma unroll
            for (int jj = 0; jj < 3; ++jj) {
                const int g = w * 3 + jj;
                gld_lds16(kp + (size_t)lane * 192 + g * 16, (char*)Ks + g * 1024);
            }
        }
        // Vt write from prefetched regs (d fixed per inst, lanes span keys: free)
#pragma unroll
        for (int jv = 0; jv < 3; ++jv)
#pragma unroll
            for (int e = 0; e < 8; ++e)
                Vt[(w * 24 + jv * 8 + e) * 72 + lane] = (ushort_t)vreg[jv][e];
        // prefetch V[kt+1]
        {
            const int ktn = (kt + 1 < SEQ / 64) ? kt + 1 : kt;
            const ushort_t* vp = Vb + (size_t)(ktn * 64 + lane) * HEAD_DIM + w * 24;
#pragma unroll
            for (int jv = 0; jv < 3; ++jv) vreg[jv] = *(const bf16x8*)(vp + jv * 8);
        }
        __syncthreads();  // Ks (vmcnt drained) + Vt visible

        // S^T = K Q^T : 4 key-tiles x 2 q-tiles x 3 d-chunks
        f32x4 sacc[4][2];
#pragma unroll
        for (int kti = 0; kti < 4; ++kti)
#pragma unroll
            for (int qi = 0; qi < 2; ++qi) sacc[kti][qi] = {0.f, 0.f, 0.f, 0.f};
#pragma unroll
        for (int kc = 0; kc < 3; ++kc) {
            bf16x8 ak[4];
#pragma unroll
            for (int kti = 0; kti < 4; ++kti)
                ak[kti] = *(const bf16x8*)&Ks[((kc * 4 + qd) * 64 + kti * 16 + c) * 8];
#pragma unroll
            for (int kti = 0; kti < 4; ++kti)
#pragma unroll
                for (int qi = 0; qi < 2; ++qi)
                    sacc[kti][qi] = MFMA16(ak[kti], aq[qi][kc], sacc[kti][qi]);
        }

        // p = 2^s; pack b64 to Ps[q][k]; per-thread partial l
        float ls0 = 0.f, ls1 = 0.f;
#pragma unroll
        for (int kti = 0; kti < 4; ++kti)
#pragma unroll
            for (int qi = 0; qi < 2; ++qi) {
                const float p0 = fast_exp2(sacc[kti][qi][0]);
                const float p1 = fast_exp2(sacc[kti][qi][1]);
                const float p2 = fast_exp2(sacc[kti][qi][2]);
                const float p3 = fast_exp2(sacc[kti][qi][3]);
                uint2 pk;
                pk.x = pk2bf(p0, p1);
                pk.y = pk2bf(p2, p3);
                *(uint2*)&Ps[w][(qi * 16 + c) * 72 + kti * 16 + qd * 4] = pk;
                const float s = (p0 + p1) + (p2 + p3);
                if (qi == 0) ls0 += s; else ls1 += s;
            }
        ls0 += __shfl_xor(ls0, 16, 64); ls0 += __shfl_xor(ls0, 32, 64);
        ls1 += __shfl_xor(ls1, 16, 64); ls1 += __shfl_xor(ls1, 32, 64);
        lrow[0] += ls0; lrow[1] += ls1;

        // O^T += V^T P^T : 6 d-tiles x 2 q-tiles x 2 k-chunks (intra-wave Ps)
#pragma unroll
        for (int kc = 0; kc < 2; ++kc) {
            bf16x8 bp[2];
#pragma unroll
            for (int qi = 0; qi < 2; ++qi)
                bp[qi] = *(const bf16x8*)&Ps[w][(qi * 16 + c) * 72 + kc * 32 + qd * 8];
#pragma unroll
            for (int jd = 0; jd < 6; ++jd) {
                const bf16x8 av = *(const bf16x8*)&Vt[(jd * 16 + c) * 72 + kc * 32 + qd * 8];
#pragma unroll
                for (int qi = 0; qi < 2; ++qi)
                    oacc[jd][qi] = MFMA16(av, bp[qi], oacc[jd][qi]);
            }
        }
    }

    // epilogue: O^T C-layout (col=q=c, row=d=qd*4+r); attn[b][s][h*96+d] bf16
#pragma unroll
    for (int qi = 0; qi < 2; ++qi) {
        const float linv = 1.0f / lrow[qi];
        const int row = bb * SEQ + q0 + w * 32 + qi * 16 + c;
        ushort_t* dst = attn + (size_t)row * D_MODEL + h * HEAD_DIM + qd * 4;
#pragma unroll
        for (int jd = 0; jd < 6; ++jd) {
            ushort4 o4;
            o4.x = f2bf(oacc[jd][qi][0] * linv);
            o4.y = f2bf(oacc[jd][qi][1] * linv);
            o4.z = f2bf(oacc[jd][qi][2] * linv);
            o4.w = f2bf(oacc[jd][qi][3] * linv);
            *(ushort4*)(dst + jd * 16) = o4;
        }
    }
}

// ---------------------------------------------------------------------------

extern "C" void kernel_launch(void* const* d_in, const int* in_sizes, int n_in,
                              void* d_out, int out_size, void* d_ws, size_t ws_size,
                              hipStream_t stream)
{
    const float* x     = (const float*)d_in[0];
    const float* w_qkv = (const float*)d_in[1];
    const float* w_out = (const float*)d_in[2];
    const float* leech = (const float*)d_in[3];
    float* out = (float*)d_out;
    char* ws = (char*)d_ws;

    ushort_t* xb    = (ushort_t*)(ws);                 // 12582912 B
    ushort_t* wqkvb = (ushort_t*)(ws + 12582912);      // 14155776 B
    ushort_t* woutb = (ushort_t*)(ws + 26738688);      //  4718592 B
    ushort_t* qb    = (ushort_t*)(ws + 31457280);      // 12582912 B each
    ushort_t* kb    = (ushort_t*)(ws + 44040192);
    ushort_t* vb    = (ushort_t*)(ws + 56623104);
    ushort_t* attnb = (ushort_t*)(ws + 69206016);      // ends 81788928

    convert_f32_bf16<<<6144, 256, 0, stream>>>(x, xb, M_TOTAL * D_MODEL);
    prep_wqkv<<<dim3(6, 192), 256, 0, stream>>>(w_qkv, leech, wqkvb);
    convert_f32_bf16<<<2304, 256, 0, stream>>>(w_out, woutb, D_MODEL * D_MODEL);

    gemm_qkv_bf16<<<dim3(N_QKV / 128, M_TOTAL / 128), 256, 0, stream>>>(
        xb, wqkvb, qb, kb, vb);

    flash_bf16<<<dim3(SEQ / 128, N_HEADS, BATCH), 256, 0, stream>>>(
        qb, kb, vb, attnb);

    gemm_out_bf16<<<dim3(D_MODEL / 128, M_TOTAL / 128), 256, 0, stream>>>(
        attnb, woutb, out);
}

// Round 4
// 282.766 us; speedup vs baseline: 8.0171x; 1.0711x over previous
//
#include <hip/hip_runtime.h>
#include <cmath>

#define D_MODEL 1536
#define N_HEADS 16
#define HEAD_DIM 96
#define SEQ 2048
#define BATCH 2
#define M_TOTAL 4096
#define N_QKV 4608
// 96^-0.5 * log2(e): fold into q so softmax exp becomes a bare v_exp_f32 (2^x)
#define QK_LOG2E 0.14724449f

typedef unsigned short ushort_t;
typedef __attribute__((ext_vector_type(8))) short bf16x8;
typedef __attribute__((ext_vector_type(4))) float f32x4;

static __device__ __forceinline__ ushort_t f2bf(float f) {
    unsigned u = __builtin_bit_cast(unsigned, f);
    u += 0x7fffu + ((u >> 16) & 1u);   // RNE
    return (ushort_t)(u >> 16);
}

static __device__ __forceinline__ unsigned pk2bf(float lo, float hi) {
#if __has_builtin(__builtin_amdgcn_cvt_pk_bf16_f32)
    auto v = __builtin_amdgcn_cvt_pk_bf16_f32(lo, hi);
    return __builtin_bit_cast(unsigned, v);
#else
    return (unsigned)f2bf(lo) | ((unsigned)f2bf(hi) << 16);
#endif
}

static __device__ __forceinline__ float fast_exp2(float x) {
#if __has_builtin(__builtin_amdgcn_exp2f)
    return __builtin_amdgcn_exp2f(x);
#else
    return __expf(x * 0.69314718056f);
#endif
}

typedef const __attribute__((address_space(1))) unsigned int* gas_t;
typedef __attribute__((address_space(3))) unsigned int* las_t;
static __device__ __forceinline__ void gld_lds16(const void* g, void* l) {
    // async global->LDS: PER-LANE global addr, LDS dest = wave-uniform base + lane*16
    __builtin_amdgcn_global_load_lds((gas_t)g, (las_t)l, 16, 0, 0);
}

#define MFMA16(a, b, c) __builtin_amdgcn_mfma_f32_16x16x32_bf16(a, b, c, 0, 0, 0)

// ---------------------------------------------------------------------------
// fp32 -> bf16 convert, 4 elems/thread
// ---------------------------------------------------------------------------
__global__ __launch_bounds__(256) void convert_f32_bf16(
    const float* __restrict__ in, ushort_t* __restrict__ out, int n)
{
    const int i = (blockIdx.x * 256 + threadIdx.x) * 4;
    if (i >= n) return;
    float4 v = *(const float4*)(in + i);
    ushort4 o;
    o.x = f2bf(v.x); o.y = f2bf(v.y); o.z = f2bf(v.z); o.w = f2bf(v.w);
    *(ushort4*)(out + i) = o;
}

// ---------------------------------------------------------------------------
// w_qkv prep: q,k rows get the leech rotation folded in (output-feature-space
// rotation within aligned 24-row groups). v rows converted as-is.
// ---------------------------------------------------------------------------
__global__ __launch_bounds__(256) void prep_wqkv(
    const float* __restrict__ W, const float* __restrict__ Kern,
    ushort_t* __restrict__ Wb)
{
    __shared__ float Kl[576];
    const int t = threadIdx.x;
    for (int i = t; i < 576; i += 256) Kl[i] = Kern[i];
    __syncthreads();
    const int g = blockIdx.y;                  // 24-row group, 0..191
    const int k = blockIdx.x * 256 + t;        // column 0..1535
    const float* src = W + (size_t)g * 24 * D_MODEL + k;
    ushort_t* dst = Wb + (size_t)g * 24 * D_MODEL + k;
    if (g < 128) {
        float in[24];
#pragma unroll
        for (int i = 0; i < 24; ++i) in[i] = src[(size_t)i * D_MODEL];
#pragma unroll
        for (int j = 0; j < 24; ++j) {
            float s = 0.f;
#pragma unroll
            for (int i = 0; i < 24; ++i) s = fmaf(in[i], Kl[i * 24 + j], s);
            dst[(size_t)j * D_MODEL] = f2bf(s);
        }
    } else {
#pragma unroll
        for (int i = 0; i < 24; ++i) dst[(size_t)i * D_MODEL] = f2bf(src[(size_t)i * D_MODEL]);
    }
}

// ---------------------------------------------------------------------------
// bf16 MFMA GEMM, C = A @ B^T. 128x128 tile, BK=64, 4 waves, 4x4 16x16/wave.
// LDS chunk-XOR swizzle (pos = chunk ^ (row&7)) applied via the gather
// addresses of global_load_lds; fragment reads land at the b128 bank floor.
// ---------------------------------------------------------------------------
__global__ __launch_bounds__(256, 4) void gemm_qkv_bf16(
    const ushort_t* __restrict__ X, const ushort_t* __restrict__ W,
    ushort_t* __restrict__ qb, ushort_t* __restrict__ kb, ushort_t* __restrict__ vtb)
{
    __shared__ ushort_t As[128 * 64];
    __shared__ ushort_t Bs[128 * 64];
    const int t = threadIdx.x;
    const int lane = t & 63, w = t >> 6;
    const int c = lane & 15, qd = lane >> 4;
    const int m0 = blockIdx.y * 128, n0 = blockIdx.x * 128;
    const int wr = (w >> 1) * 64, wc = (w & 1) * 64;
    const int lr = lane >> 3;               // row within 8-row inst span
    const int lc = (lane & 7) ^ lr;         // xor-swizzled data k-chunk
    const char* Xb = (const char*)X;
    const char* Wp = (const char*)W;
    const size_t rowb = 2 * D_MODEL;

    f32x4 acc[4][4];
#pragma unroll
    for (int i = 0; i < 4; ++i)
#pragma unroll
        for (int j = 0; j < 4; ++j) acc[i][j] = {0.f, 0.f, 0.f, 0.f};

    for (int k0 = 0; k0 < D_MODEL; k0 += 64) {
        __syncthreads();
#pragma unroll
        for (int j = 0; j < 4; ++j) {
            const int g = w * 4 + j;        // inst 0..15, covers rows g*8..g*8+7
            const int row = g * 8 + lr;
            gld_lds16(Xb + (size_t)(m0 + row) * rowb + k0 * 2 + lc * 16,
                      (char*)As + g * 1024);
            gld_lds16(Wp + (size_t)(n0 + row) * rowb + k0 * 2 + lc * 16,
                      (char*)Bs + g * 1024);
        }
        __syncthreads();
#pragma unroll
        for (int kc = 0; kc < 2; ++kc) {
            const int sx = ((kc * 4 + qd) ^ (c & 7)) * 16;
            bf16x8 af[4], bfr[4];
#pragma unroll
            for (int i = 0; i < 4; ++i)
                af[i] = *(const bf16x8*)((const char*)As + (wr + i * 16 + c) * 128 + sx);
#pragma unroll
            for (int j = 0; j < 4; ++j)
                bfr[j] = *(const bf16x8*)((const char*)Bs + (wc + j * 16 + c) * 128 + sx);
#pragma unroll
            for (int i = 0; i < 4; ++i)
#pragma unroll
                for (int j = 0; j < 4; ++j)
                    acc[i][j] = MFMA16(af[i], bfr[j], acc[i][j]);
        }
    }
    // epilogue: q/k scatter bf16 into [b][h][s][96] (q gets QK_LOG2E folded);
    // v written TRANSPOSED as V^T [b][h][d][s] with packed b64 stores.
#pragma unroll
    for (int j = 0; j < 4; ++j) {
        const int n = n0 + wc + j * 16 + c;
        const int which = n / D_MODEL;      // wave-uniform per j
        const int rem = n % D_MODEL;
        const int head = rem / HEAD_DIM;
        const int d = rem % HEAD_DIM;
        if (which < 2) {
            ushort_t* dst = which == 0 ? qb : kb;
            const float sc2 = which == 0 ? QK_LOG2E : 1.0f;
#pragma unroll
            for (int i = 0; i < 4; ++i)
#pragma unroll
                for (int r = 0; r < 4; ++r) {
                    const int m = m0 + wr + i * 16 + qd * 4 + r;
                    const int b_ = m >> 11, s_ = m & (SEQ - 1);
                    dst[((size_t)(b_ * N_HEADS + head) * SEQ + s_) * HEAD_DIM + d] =
                        f2bf(acc[i][j][r] * sc2);
                }
        } else {
            const int b_ = m0 >> 11;
            const int sb = (m0 & (SEQ - 1)) + wr + qd * 4;
            ushort_t* dstv = vtb + ((size_t)(b_ * N_HEADS + head) * HEAD_DIM + d) * SEQ;
#pragma unroll
            for (int i = 0; i < 4; ++i) {
                ushort4 o4;
                o4.x = f2bf(acc[i][j][0]); o4.y = f2bf(acc[i][j][1]);
                o4.z = f2bf(acc[i][j][2]); o4.w = f2bf(acc[i][j][3]);
                *(ushort4*)&dstv[sb + i * 16] = o4;
            }
        }
    }
}

__global__ __launch_bounds__(256, 4) void gemm_out_bf16(
    const ushort_t* __restrict__ A, const ushort_t* __restrict__ W,
    float* __restrict__ C)
{
    __shared__ ushort_t As[128 * 64];
    __shared__ ushort_t Bs[128 * 64];
    const int t = threadIdx.x;
    const int lane = t & 63, w = t >> 6;
    const int c = lane & 15, qd = lane >> 4;
    const int m0 = blockIdx.y * 128, n0 = blockIdx.x * 128;
    const int wr = (w >> 1) * 64, wc = (w & 1) * 64;
    const int lr = lane >> 3;
    const int lc = (lane & 7) ^ lr;
    const char* Ab = (const char*)A;
    const char* Wp = (const char*)W;
    const size_t rowb = 2 * D_MODEL;

    f32x4 acc[4][4];
#pragma unroll
    for (int i = 0; i < 4; ++i)
#pragma unroll
        for (int j = 0; j < 4; ++j) acc[i][j] = {0.f, 0.f, 0.f, 0.f};

    for (int k0 = 0; k0 < D_MODEL; k0 += 64) {
        __syncthreads();
#pragma unroll
        for (int j = 0; j < 4; ++j) {
            const int g = w * 4 + j;
            const int row = g * 8 + lr;
            gld_lds16(Ab + (size_t)(m0 + row) * rowb + k0 * 2 + lc * 16,
                      (char*)As + g * 1024);
            gld_lds16(Wp + (size_t)(n0 + row) * rowb + k0 * 2 + lc * 16,
                      (char*)Bs + g * 1024);
        }
        __syncthreads();
#pragma unroll
        for (int kc = 0; kc < 2; ++kc) {
            const int sx = ((kc * 4 + qd) ^ (c & 7)) * 16;
            bf16x8 af[4], bfr[4];
#pragma unroll
            for (int i = 0; i < 4; ++i)
                af[i] = *(const bf16x8*)((const char*)As + (wr + i * 16 + c) * 128 + sx);
#pragma unroll
            for (int j = 0; j < 4; ++j)
                bfr[j] = *(const bf16x8*)((const char*)Bs + (wc + j * 16 + c) * 128 + sx);
#pragma unroll
            for (int i = 0; i < 4; ++i)
#pragma unroll
                for (int j = 0; j < 4; ++j)
                    acc[i][j] = MFMA16(af[i], bfr[j], acc[i][j]);
        }
    }
#pragma unroll
    for (int i = 0; i < 4; ++i)
#pragma unroll
        for (int j = 0; j < 4; ++j)
#pragma unroll
            for (int r = 0; r < 4; ++r)
                C[(size_t)(m0 + wr + i * 16 + qd * 4 + r) * D_MODEL + n0 + wc + j * 16 + c] =
                    acc[i][j][r];
}

// ---------------------------------------------------------------------------
// MFMA flash attention v4 (no-max softmax; S^T formulation; all-gather staging).
// Block = 128 q x one (b,h); 4 waves x 32 q. BK=64 keys/iter.
//   S^T = K·Q^T  (A=K rows from chunk-major LDS, B=Q regs)
//   p = 2^s; l via in-reg sum + 2 shuffles
//   P packed to per-wave LDS [q][k] as b64 writes (no barrier)
//   O^T = V^T·P^T (A=Vt rows from xor-swizzled LDS, B=Ps rows)
// K staged chunk-major [12][64][8]; Vt staged from global V^T [b][h][d][s]
// via xor-swizzled gather — no in-kernel transpose.
// ---------------------------------------------------------------------------
__global__ __launch_bounds__(256, 3) void flash_bf16(
    const ushort_t* __restrict__ Q, const ushort_t* __restrict__ K,
    const ushort_t* __restrict__ VT, ushort_t* __restrict__ attn)
{
    __shared__ ushort_t Ks[12 * 64 * 8];  // chunk-major: (d-chunk, key, 8)
    __shared__ ushort_t Vt[96 * 64];      // [d][key], xor-swizzled 16B chunks
    __shared__ ushort_t Ps[4][32 * 72];   // per-wave [q][k], pad 64->72

    const int t = threadIdx.x;
    const int lane = t & 63, w = t >> 6;
    const int c = lane & 15, qd = lane >> 4;
    const int lr = lane >> 3;             // staging row-in-8
    const int lc = (lane & 7) ^ lr;       // xor-swizzled data chunk
    const int h = blockIdx.y, bb = blockIdx.z;
    const int q0 = blockIdx.x * 128;
    const size_t base = ((size_t)(bb * N_HEADS + h)) * SEQ * HEAD_DIM;
    const ushort_t* Qb = Q + base;
    const char* Kb = (const char*)(K + base);
    const ushort_t* VTb = VT + base;      // [96][2048] within (b,h)

    // Q B-operand fragments (resident all kernel): B[n=q][k=d]
    bf16x8 aq[2][3];
#pragma unroll
    for (int qi = 0; qi < 2; ++qi)
#pragma unroll
        for (int kc = 0; kc < 3; ++kc)
            aq[qi][kc] = *(const bf16x8*)(Qb +
                (size_t)(q0 + w * 32 + qi * 16 + c) * HEAD_DIM + kc * 32 + qd * 8);

    f32x4 oacc[6][2];
#pragma unroll
    for (int jd = 0; jd < 6; ++jd)
#pragma unroll
        for (int qi = 0; qi < 2; ++qi) oacc[jd][qi] = {0.f, 0.f, 0.f, 0.f};
    float lrow[2] = {0.f, 0.f};

    for (int kt = 0; kt < SEQ / 64; ++kt) {
        __syncthreads();  // prior iter's Ks/Vt readers done
        // async K[kt] staging, chunk-major, per-lane gather (stride 192B)
        {
            const char* kp = Kb + (size_t)kt * 64 * 192;
#pragma unroll
            for (int jj = 0; jj < 3; ++jj) {
                const int g = w * 3 + jj;
                gld_lds16(kp + (size_t)lane * 192 + g * 16, (char*)Ks + g * 1024);
            }
        }
        // async Vt staging from global V^T, xor-swizzled chunks
#pragma unroll
        for (int jj = 0; jj < 3; ++jj) {
            const int g = w * 3 + jj;         // d rows g*8..g*8+7
            const int d = g * 8 + lr;
            gld_lds16((const char*)(VTb + (size_t)d * SEQ + kt * 64 + lc * 8),
                      (char*)Vt + g * 1024);
        }
        __syncthreads();  // Ks/Vt (vmcnt drained) visible

        // S^T = K Q^T : 4 key-tiles x 2 q-tiles x 3 d-chunks
        f32x4 sacc[4][2];
#pragma unroll
        for (int kti = 0; kti < 4; ++kti)
#pragma unroll
            for (int qi = 0; qi < 2; ++qi) sacc[kti][qi] = {0.f, 0.f, 0.f, 0.f};
#pragma unroll
        for (int kc = 0; kc < 3; ++kc) {
            bf16x8 ak[4];
#pragma unroll
            for (int kti = 0; kti < 4; ++kti)
                ak[kti] = *(const bf16x8*)&Ks[((kc * 4 + qd) * 64 + kti * 16 + c) * 8];
#pragma unroll
            for (int kti = 0; kti < 4; ++kti)
#pragma unroll
                for (int qi = 0; qi < 2; ++qi)
                    sacc[kti][qi] = MFMA16(ak[kti], aq[qi][kc], sacc[kti][qi]);
        }

        // p = 2^s; pack b64 to Ps[q][k]; per-thread partial l
        float ls0 = 0.f, ls1 = 0.f;
#pragma unroll
        for (int kti = 0; kti < 4; ++kti)
#pragma unroll
            for (int qi = 0; qi < 2; ++qi) {
                const float p0 = fast_exp2(sacc[kti][qi][0]);
                const float p1 = fast_exp2(sacc[kti][qi][1]);
                const float p2 = fast_exp2(sacc[kti][qi][2]);
                const float p3 = fast_exp2(sacc[kti][qi][3]);
                uint2 pk;
                pk.x = pk2bf(p0, p1);
                pk.y = pk2bf(p2, p3);
                *(uint2*)&Ps[w][(qi * 16 + c) * 72 + kti * 16 + qd * 4] = pk;
                const float s = (p0 + p1) + (p2 + p3);
                if (qi == 0) ls0 += s; else ls1 += s;
            }
        ls0 += __shfl_xor(ls0, 16, 64); ls0 += __shfl_xor(ls0, 32, 64);
        ls1 += __shfl_xor(ls1, 16, 64); ls1 += __shfl_xor(ls1, 32, 64);
        lrow[0] += ls0; lrow[1] += ls1;

        // O^T += V^T P^T : 6 d-tiles x 2 q-tiles x 2 k-chunks (intra-wave Ps)
#pragma unroll
        for (int kc = 0; kc < 2; ++kc) {
            bf16x8 bp[2];
#pragma unroll
            for (int qi = 0; qi < 2; ++qi)
                bp[qi] = *(const bf16x8*)&Ps[w][(qi * 16 + c) * 72 + kc * 32 + qd * 8];
#pragma unroll
            for (int jd = 0; jd < 6; ++jd) {
                const int sx = ((kc * 4 + qd) ^ (c & 7)) * 16;
                const bf16x8 av =
                    *(const bf16x8*)((const char*)Vt + (jd * 16 + c) * 128 + sx);
#pragma unroll
                for (int qi = 0; qi < 2; ++qi)
                    oacc[jd][qi] = MFMA16(av, bp[qi], oacc[jd][qi]);
            }
        }
    }

    // epilogue: O^T C-layout (col=q=c, row=d=qd*4+r); attn[b][s][h*96+d] bf16
#pragma unroll
    for (int qi = 0; qi < 2; ++qi) {
        const float linv = 1.0f / lrow[qi];
        const int row = bb * SEQ + q0 + w * 32 + qi * 16 + c;
        ushort_t* dst = attn + (size_t)row * D_MODEL + h * HEAD_DIM + qd * 4;
#pragma unroll
        for (int jd = 0; jd < 6; ++jd) {
            ushort4 o4;
            o4.x = f2bf(oacc[jd][qi][0] * linv);
            o4.y = f2bf(oacc[jd][qi][1] * linv);
            o4.z = f2bf(oacc[jd][qi][2] * linv);
            o4.w = f2bf(oacc[jd][qi][3] * linv);
            *(ushort4*)(dst + jd * 16) = o4;
        }
    }
}

// ---------------------------------------------------------------------------

extern "C" void kernel_launch(void* const* d_in, const int* in_sizes, int n_in,
                              void* d_out, int out_size, void* d_ws, size_t ws_size,
                              hipStream_t stream)
{
    const float* x     = (const float*)d_in[0];
    const float* w_qkv = (const float*)d_in[1];
    const float* w_out = (const float*)d_in[2];
    const float* leech = (const float*)d_in[3];
    float* out = (float*)d_out;
    char* ws = (char*)d_ws;

    ushort_t* xb    = (ushort_t*)(ws);                 // 12582912 B
    ushort_t* wqkvb = (ushort_t*)(ws + 12582912);      // 14155776 B
    ushort_t* woutb = (ushort_t*)(ws + 26738688);      //  4718592 B
    ushort_t* qb    = (ushort_t*)(ws + 31457280);      // 12582912 B each
    ushort_t* kb    = (ushort_t*)(ws + 44040192);
    ushort_t* vtb   = (ushort_t*)(ws + 56623104);      // V^T [b][h][96][2048]
    ushort_t* attnb = (ushort_t*)(ws + 69206016);      // ends 81788928

    convert_f32_bf16<<<6144, 256, 0, stream>>>(x, xb, M_TOTAL * D_MODEL);
    prep_wqkv<<<dim3(6, 192), 256, 0, stream>>>(w_qkv, leech, wqkvb);
    convert_f32_bf16<<<2304, 256, 0, stream>>>(w_out, woutb, D_MODEL * D_MODEL);

    gemm_qkv_bf16<<<dim3(N_QKV / 128, M_TOTAL / 128), 256, 0, stream>>>(
        xb, wqkvb, qb, kb, vtb);

    flash_bf16<<<dim3(SEQ / 128, N_HEADS, BATCH), 256, 0, stream>>>(
        qb, kb, vtb, attnb);

    gemm_out_bf16<<<dim3(D_MODEL / 128, M_TOTAL / 128), 256, 0, stream>>>(
        attnb, woutb, out);
}